// Round 8
// baseline (7246.228 us; speedup 1.0000x reference)
//
#include <hip/hip_runtime.h>

// Problem constants
#define B_    64
#define T_    512
#define KDIM  1024
#define HID_  1024

// Fused tile sizes
#define BM 128  // t-chunk per block iteration (4 chunks)
#define BN 64   // h-tile per block
#define BK 16   // one numpy 4x-unrolled SIMD block (4 lanes x 4 vectors)
#define LDA 20  // padded LDS row: 16 + 4 floats (keeps float4 align, breaks pow2)
#define NSLICE ((T_ / BM) * (KDIM / BK))   // 4 * 64 = 256 staging slices

// f32 correctly rounded from python float math.exp(-1.0/20.0)
#define ALPHA_F 0.95122942450071400909f

// Bit-exact replication of the harness numpy f32 reference (einsum
// optimize=False, SSE baseline: 4-lane f32 accumulator, mul+add separate,
// per 16-k block chained adds == per-lane descending-q accumulation, blocks
// ascending k, hadd tree (l0+l1)+(l2+l3), one f32 bias add; f32 scan).
// R8 vs R7 (1.70 ms, LDS-bound): 8x4 micro-tile (LDS bytes/MAC x0.75),
// lane-paired accumulators (invite v_pk_mul/add_f32 — per-lane rounding
// identical), double-buffered staging with 1 barrier per k-slice.
// Per-element accumulation chain is UNCHANGED (only thread->element mapping).
__global__ __launch_bounds__(256, 2) void snn_np_exact2(
    const float* __restrict__ x,     // [B,T,K] f32
    const float* __restrict__ W,     // [H,K] f32
    const float* __restrict__ bias,  // [H] f32
    float* __restrict__ spikes,      // [B,T,H] f32 out
    float* __restrict__ memf)        // [B,H] f32 out
{
#pragma clang fp contract(off)       // numpy SSE path has no FMA: mul+add only
    __shared__ float As[2][BM][LDA];   // 20.0 KB
    __shared__ float Bs[2][BN][LDA];   // 10.0 KB
    __shared__ float Ism[BM][BN + 1];  // 33.3 KB
    __shared__ float bsh[BN];

    const int tid = threadIdx.x;
    const int bb  = blockIdx.x;             // batch index
    const int h0  = blockIdx.y * BN;        // h tile origin

    const int tx = tid & 15;                // h micro-index (4 cols, stride 16)
    const int ty = tid >> 4;                // t micro-index (8 rows, stride 16)

    // staging: A tile 128x16 = 512 float4 (2/thread), B tile 64x16 = 256 (1/thread)
    const int srow = tid >> 2;              // 0..63
    const int scol = (tid & 3) << 2;        // 0,4,8,12

    if (tid < BN) bsh[tid] = bias[h0 + tid];

    float mem = 0.0f;                       // threads 0..63 carry h = h0+tid

    // prologue: stage slice 0 (chunk 0, k0=0) into buffer 0
    {
        const float4 av0 = *(const float4*)&x[((size_t)(bb * T_ + srow)) * KDIM + scol];
        const float4 av1 = *(const float4*)&x[((size_t)(bb * T_ + srow + 64)) * KDIM + scol];
        const float4 wv  = *(const float4*)&W[((size_t)(h0 + srow)) * KDIM + scol];
        *(float4*)&As[0][srow][scol]      = av0;
        *(float4*)&As[0][srow + 64][scol] = av1;
        *(float4*)&Bs[0][srow][scol]      = wv;
    }

    int cur = 0;
    int slice = 0;
    for (int c = 0; c < T_ / BM; ++c) {
        // lane-paired numpy accumulators: p01 = lanes {0,1}, p23 = lanes {2,3}
        float2 p01[8][4], p23[8][4];
#pragma unroll
        for (int j = 0; j < 8; ++j)
#pragma unroll
            for (int i = 0; i < 4; ++i) {
                p01[j][i] = make_float2(0.0f, 0.0f);
                p23[j][i] = make_float2(0.0f, 0.0f);
            }

        for (int k0i = 0; k0i < KDIM / BK; ++k0i) {
            __syncthreads();   // buf[cur] staged; prev iter's reads of buf[cur^1] done
            // prefetch next slice into buf[cur^1]
            const int ns = slice + 1;
            if (ns < NSLICE) {
                const int nt0 = (ns >> 6) * BM;
                const int nk  = (ns & 63) << 4;
                const int nb  = cur ^ 1;
                const float4 av0 = *(const float4*)&x[((size_t)(bb * T_ + nt0 + srow)) * KDIM + nk + scol];
                const float4 av1 = *(const float4*)&x[((size_t)(bb * T_ + nt0 + srow + 64)) * KDIM + nk + scol];
                const float4 wv  = *(const float4*)&W[((size_t)(h0 + srow)) * KDIM + nk + scol];
                *(float4*)&As[nb][srow][scol]      = av0;
                *(float4*)&As[nb][srow + 64][scol] = av1;
                *(float4*)&Bs[nb][srow][scol]      = wv;
            }
            // q = 3,2,1,0: per-lane acc += a[4q+l]*b[4q+l] (mul, then add) —
            // bitwise equal to numpy's chained a0b0+(a1b1+(a2b2+(a3b3+acc)))
#pragma unroll
            for (int q = 3; q >= 0; --q) {
                float4 a4[8], b4[4];
#pragma unroll
                for (int j = 0; j < 8; ++j)
                    a4[j] = *(const float4*)&As[cur][ty + 16 * j][q << 2];
#pragma unroll
                for (int i = 0; i < 4; ++i)
                    b4[i] = *(const float4*)&Bs[cur][tx + 16 * i][q << 2];
#pragma unroll
                for (int j = 0; j < 8; ++j)
#pragma unroll
                    for (int i = 0; i < 4; ++i) {
                        const float m0 = a4[j].x * b4[i].x;   // rounded muls
                        const float m1 = a4[j].y * b4[i].y;
                        const float m2 = a4[j].z * b4[i].z;
                        const float m3 = a4[j].w * b4[i].w;
                        p01[j][i].x = p01[j][i].x + m0;       // rounded adds
                        p01[j][i].y = p01[j][i].y + m1;
                        p23[j][i].x = p23[j][i].x + m2;
                        p23[j][i].y = p23[j][i].y + m3;
                    }
            }
            cur ^= 1;
            ++slice;
        }

        // hadd tree (l0+l1)+(l2+l3), then bias, write I chunk to LDS.
        // Prev chunk's scan reads of Ism are ordered before these writes by
        // the 64 slice barriers in between.
#pragma unroll
        for (int j = 0; j < 8; ++j)
#pragma unroll
            for (int i = 0; i < 4; ++i) {
                const float s01 = p01[j][i].x + p01[j][i].y;
                const float s23 = p23[j][i].x + p23[j][i].y;
                Ism[ty + 16 * j][tx + 16 * i] = (s01 + s23) + bsh[tx + 16 * i];
            }
        __syncthreads();

        // f32 LIF scan over this chunk; one thread per h.
        if (tid < BN) {
            const size_t srow0 = ((size_t)(bb * T_ + c * BM)) * HID_ + h0 + tid;
#pragma unroll 4
            for (int t = 0; t < BM; ++t) {
                const float It = Ism[t][tid];
                const float am = ALPHA_F * mem;   // rounded mul
                mem = am + It;                    // rounded add
                const bool fire = (mem >= 1.0f);
                spikes[srow0 + (size_t)t * HID_] = fire ? 1.0f : 0.0f;
                if (fire) mem = 0.0f;
            }
        }
        // next chunk's first slice barrier orders the scan before anything else
    }

    if (tid < BN) memf[(size_t)bb * HID_ + h0 + tid] = mem;
}

extern "C" void kernel_launch(void* const* d_in, const int* in_sizes, int n_in,
                              void* d_out, int out_size, void* d_ws, size_t ws_size,
                              hipStream_t stream) {
    const float* x    = (const float*)d_in[0];   // [B,T,K] f32
    const float* W    = (const float*)d_in[1];   // [H,K] f32
    const float* bias = (const float*)d_in[2];   // [H] f32
    float* out    = (float*)d_out;
    float* spikes = out;                          // [B,T,H]
    float* memf   = out + (size_t)B_ * T_ * HID_; // [B,H]

    dim3 grid(B_, HID_ / BN);   // 64 x 16 = 1024 blocks
    snn_np_exact2<<<grid, dim3(256), 0, stream>>>(x, W, bias, spikes, memf);
}

// Round 9
// 5169.566 us; speedup vs baseline: 1.4017x; 1.4017x over previous
//
#include <hip/hip_runtime.h>

// Problem constants
#define B_    64
#define T_    512
#define KDIM  1024
#define HID_  1024

// Fused tile sizes
#define BM 128  // t-chunk per block iteration (4 chunks)
#define BN 64   // h-tile per block
#define BK 16   // one numpy 4x-unrolled SIMD block (4 lanes x 4 vectors)
#define LDA 20  // padded LDS row: 16 + 4 floats (keeps float4 align, breaks pow2)

// f32 correctly rounded from python float math.exp(-1.0/20.0)
#define ALPHA_F 0.95122942450071400909f

// Bit-faithful replication of the harness numpy f32 reference (einsum
// optimize=False, SSE baseline: 4-lane f32 accumulator, mul+add separate,
// per 16-k block chained adds == per-lane descending-q accumulation, blocks
// ascending k, hadd tree (l0+l1)+(l2+l3), one f32 bias add; f32 scan).
// Arithmetic identical to R8 (which PASSED).
//
// R9 vs R8 (7.25 ms, spilled): the RA targets 4 waves/EU (128-VGPR cap) unless
// pinned — __launch_bounds__(256,2) is only a lower bound on waves/EU, so the
// 8x4 tile's ~200 regs spilled to scratch (15 GB writes/dispatch).
// Fix: amdgpu_waves_per_eu(2,2) pins 2 waves/EU -> 256-reg budget. Also drop
// the double-buffer prefetch (12+ long-lived regs, pure pressure; barriers
// were not the bottleneck).
__global__ __attribute__((amdgpu_flat_work_group_size(256, 256),
                          amdgpu_waves_per_eu(2, 2)))
void snn_np_exact3(
    const float* __restrict__ x,     // [B,T,K] f32
    const float* __restrict__ W,     // [H,K] f32
    const float* __restrict__ bias,  // [H] f32
    float* __restrict__ spikes,      // [B,T,H] f32 out
    float* __restrict__ memf)        // [B,H] f32 out
{
#pragma clang fp contract(off)       // numpy SSE path has no FMA: mul+add only
    __shared__ float As[BM][LDA];      // 10.0 KB
    __shared__ float Bs[BN][LDA];      //  5.0 KB
    __shared__ float Ism[BM][BN + 1];  // 33.3 KB
    __shared__ float bsh[BN];

    const int tid = threadIdx.x;
    const int bb  = blockIdx.x;             // batch index
    const int h0  = blockIdx.y * BN;        // h tile origin

    const int tx = tid & 15;                // h micro-index (4 cols, stride 16)
    const int ty = tid >> 4;                // t micro-index (8 rows, stride 16)

    // staging: A tile 128x16 = 512 float4 (2/thread), B tile 64x16 = 256 (1/thread)
    const int srow = tid >> 2;              // 0..63
    const int scol = (tid & 3) << 2;        // 0,4,8,12

    if (tid < BN) bsh[tid] = bias[h0 + tid];

    float mem = 0.0f;                       // threads 0..63 carry h = h0+tid

    for (int c = 0; c < T_ / BM; ++c) {
        const int t0 = c * BM;
        // lane-paired numpy accumulators: p01 = lanes {0,1}, p23 = lanes {2,3}
        float2 p01[8][4], p23[8][4];
#pragma unroll
        for (int j = 0; j < 8; ++j)
#pragma unroll
            for (int i = 0; i < 4; ++i) {
                p01[j][i] = make_float2(0.0f, 0.0f);
                p23[j][i] = make_float2(0.0f, 0.0f);
            }

        for (int k0 = 0; k0 < KDIM; k0 += BK) {   // numpy blocks, ascending
            __syncthreads();   // prev slice's As/Bs readers done (+ bsh/Ism users)
            {
                const float4 av0 = *(const float4*)&x[((size_t)(bb * T_ + t0 + srow)) * KDIM + k0 + scol];
                const float4 av1 = *(const float4*)&x[((size_t)(bb * T_ + t0 + srow + 64)) * KDIM + k0 + scol];
                const float4 wv  = *(const float4*)&W[((size_t)(h0 + srow)) * KDIM + k0 + scol];
                *(float4*)&As[srow][scol]      = av0;
                *(float4*)&As[srow + 64][scol] = av1;
                *(float4*)&Bs[srow][scol]      = wv;
            }
            __syncthreads();
            // q = 3,2,1,0: per-lane acc += a[4q+l]*b[4q+l] (mul, then add) —
            // bitwise equal to numpy's chained a0b0+(a1b1+(a2b2+(a3b3+acc)))
#pragma unroll
            for (int q = 3; q >= 0; --q) {
                float4 a4[8], b4[4];
#pragma unroll
                for (int j = 0; j < 8; ++j)
                    a4[j] = *(const float4*)&As[ty + 16 * j][q << 2];
#pragma unroll
                for (int i = 0; i < 4; ++i)
                    b4[i] = *(const float4*)&Bs[tx + 16 * i][q << 2];
#pragma unroll
                for (int j = 0; j < 8; ++j)
#pragma unroll
                    for (int i = 0; i < 4; ++i) {
                        const float m0 = a4[j].x * b4[i].x;   // rounded muls
                        const float m1 = a4[j].y * b4[i].y;
                        const float m2 = a4[j].z * b4[i].z;
                        const float m3 = a4[j].w * b4[i].w;
                        p01[j][i].x = p01[j][i].x + m0;       // rounded adds
                        p01[j][i].y = p01[j][i].y + m1;
                        p23[j][i].x = p23[j][i].x + m2;
                        p23[j][i].y = p23[j][i].y + m3;
                    }
            }
        }

        // hadd tree (l0+l1)+(l2+l3), then bias, write I chunk to LDS.
        // Prev chunk's scan reads of Ism are ordered before these writes by
        // the 128 slice barriers in between.
#pragma unroll
        for (int j = 0; j < 8; ++j)
#pragma unroll
            for (int i = 0; i < 4; ++i) {
                const float s01 = p01[j][i].x + p01[j][i].y;
                const float s23 = p23[j][i].x + p23[j][i].y;
                Ism[ty + 16 * j][tx + 16 * i] = (s01 + s23) + bsh[tx + 16 * i];
            }
        __syncthreads();

        // f32 LIF scan over this chunk; one thread per h.
        if (tid < BN) {
            const size_t srow0 = ((size_t)(bb * T_ + t0)) * HID_ + h0 + tid;
#pragma unroll 4
            for (int t = 0; t < BM; ++t) {
                const float It = Ism[t][tid];
                const float am = ALPHA_F * mem;   // rounded mul
                mem = am + It;                    // rounded add
                const bool fire = (mem >= 1.0f);
                spikes[srow0 + (size_t)t * HID_] = fire ? 1.0f : 0.0f;
                if (fire) mem = 0.0f;
            }
        }
        // next chunk's first slice barrier orders the scan before the next
        // epilogue's Ism writes (staging only touches As/Bs).
    }

    if (tid < BN) memf[(size_t)bb * HID_ + h0 + tid] = mem;
}

extern "C" void kernel_launch(void* const* d_in, const int* in_sizes, int n_in,
                              void* d_out, int out_size, void* d_ws, size_t ws_size,
                              hipStream_t stream) {
    const float* x    = (const float*)d_in[0];   // [B,T,K] f32
    const float* W    = (const float*)d_in[1];   // [H,K] f32
    const float* bias = (const float*)d_in[2];   // [H] f32
    float* out    = (float*)d_out;
    float* spikes = out;                          // [B,T,H]
    float* memf   = out + (size_t)B_ * T_ * HID_; // [B,H]

    dim3 grid(B_, HID_ / BN);   // 64 x 16 = 1024 blocks
    snn_np_exact3<<<grid, dim3(256), 0, stream>>>(x, W, bias, spikes, memf);
}

// Round 10
// 1573.685 us; speedup vs baseline: 4.6046x; 3.2850x over previous
//
#include <hip/hip_runtime.h>

// Problem constants
#define B_    64
#define T_    512
#define KDIM  1024
#define HID_  1024

// Fused tile sizes (R7 skeleton: the proven no-spill configuration)
#define BM 64   // t-chunk per block iteration (8 chunks)
#define BN 64   // h-tile per block
#define BK 32   // TWO numpy 16-k blocks staged per barrier pair
#define LDA 36  // padded LDS row: 32 + 4 floats (float4-aligned, breaks pow2)

// f32 correctly rounded from python float math.exp(-1.0/20.0)
#define ALPHA_F 0.95122942450071400909f

typedef float v4f __attribute__((ext_vector_type(4)));
typedef float v2f __attribute__((ext_vector_type(2)));

// Bit-faithful replication of the harness numpy f32 reference (einsum
// optimize=False, SSE baseline): per output element 4 f32 accumulator lanes
// (lane l sums k = l mod 4), per 16-k block chained adds == per-lane
// descending-q accumulation (q=3,2,1,0), 16-k blocks ascending, mul and add
// separately rounded (no FMA), horizontal sum (l0+l1)+(l2+l3), one f32 bias
// add; f32 scan mem = alpha*mem + I (2 rounded ops), spike = mem>=1, reset.
// This chain is byte-identical to R6/R7/R8/R9 (all PASSED).
//
// R10 vs R7 (1.70 ms, VALU-issue-bound at the scalar mul/add floor 0.87 ms):
//  - lane-paired v2f accumulators/fragments -> v_pk_mul_f32/v_pk_add_f32
//    (per-lane rounding identical; halves VALU instruction count)
//  - BK=32: two numpy blocks per staging barrier (1024 -> 512 barriers)
//  - 4x4 micro-tile kept: 64 acc VGPRs, ~120 total — no spill under (256,2).
//    (8x4 tile needs ~200 regs and spilled in R8/R9: 15 GB scratch traffic.)
__global__ __launch_bounds__(256, 2) void snn_np_pk(
    const float* __restrict__ x,     // [B,T,K] f32
    const float* __restrict__ W,     // [H,K] f32
    const float* __restrict__ bias,  // [H] f32
    float* __restrict__ spikes,      // [B,T,H] f32 out
    float* __restrict__ memf)        // [B,H] f32 out
{
#pragma clang fp contract(off)       // numpy SSE path has no FMA: mul+add only
    __shared__ float As[BM][LDA];      // 9.0 KB
    __shared__ float Bs[BN][LDA];      // 9.0 KB
    __shared__ float Ism[BM][BN + 1];  // 16.3 KB
    __shared__ float bsh[BN];

    const int tid = threadIdx.x;
    const int bb  = blockIdx.x;             // batch index
    const int h0  = blockIdx.y * BN;        // h tile origin

    const int tx = tid & 15;                // h micro-index (4 cols, stride 16)
    const int ty = tid >> 4;                // t micro-index (4 rows, stride 16)

    // staging: tile 64x32 = 512 float4; thread stages float4 #tid and #tid+256
    // (linear index f: row = f>>3, col = (f&7)*4 — lane-consecutive = coalesced)
    const int sr0 = tid >> 3;               // rows 0..31   (f = tid)
    const int sr1 = 32 + sr0;               // rows 32..63  (f = tid + 256)
    const int sc  = (tid & 7) << 2;         // col 0,4,..,28

    if (tid < BN) bsh[tid] = bias[h0 + tid];

    float mem = 0.0f;                       // threads 0..63 carry h = h0+tid

    for (int c = 0; c < T_ / BM; ++c) {
        const int t0 = c * BM;
        // numpy 4-lane accumulators, lane-paired: p01 = lanes {0,1}, p23 = {2,3}
        v2f p01[4][4], p23[4][4];
#pragma unroll
        for (int j = 0; j < 4; ++j)
#pragma unroll
            for (int i = 0; i < 4; ++i) {
                p01[j][i] = (v2f)(0.0f);
                p23[j][i] = (v2f)(0.0f);
            }

        for (int k0 = 0; k0 < KDIM; k0 += BK) {
            __syncthreads();   // prev slice's As/Bs readers done (+ bsh/Ism users)
            {
                const size_t xrow = (size_t)(bb * T_ + t0) * KDIM + k0;
                const size_t wrow = (size_t)h0 * KDIM + k0;
                const float4 a0 = *(const float4*)&x[xrow + (size_t)sr0 * KDIM + sc];
                const float4 a1 = *(const float4*)&x[xrow + (size_t)sr1 * KDIM + sc];
                const float4 w0 = *(const float4*)&W[wrow + (size_t)sr0 * KDIM + sc];
                const float4 w1 = *(const float4*)&W[wrow + (size_t)sr1 * KDIM + sc];
                *(float4*)&As[sr0][sc] = a0;
                *(float4*)&As[sr1][sc] = a1;
                *(float4*)&Bs[sr0][sc] = w0;
                *(float4*)&Bs[sr1][sc] = w1;
            }
            __syncthreads();
            // two numpy 16-k blocks, ascending; q = 3,2,1,0 within each —
            // per-lane acc += a[16kb+4q+l]*b[16kb+4q+l], mul then add:
            // bitwise equal to numpy's chained a0b0+(a1b1+(a2b2+(a3b3+acc)))
#pragma unroll
            for (int kb = 0; kb < 2; ++kb) {
#pragma unroll
                for (int q = 3; q >= 0; --q) {
                    const int qc = (kb << 4) + (q << 2);
                    v2f a01[4], a23[4], b01[4], b23[4];
#pragma unroll
                    for (int j = 0; j < 4; ++j) {
                        const v4f a = *(const v4f*)&As[ty + 16 * j][qc];
                        a01[j] = a.xy; a23[j] = a.zw;
                    }
#pragma unroll
                    for (int i = 0; i < 4; ++i) {
                        const v4f b = *(const v4f*)&Bs[tx + 16 * i][qc];
                        b01[i] = b.xy; b23[i] = b.zw;
                    }
#pragma unroll
                    for (int j = 0; j < 4; ++j)
#pragma unroll
                        for (int i = 0; i < 4; ++i) {
                            const v2f m01 = a01[j] * b01[i];   // packed rounded muls
                            const v2f m23 = a23[j] * b23[i];
                            p01[j][i] = p01[j][i] + m01;       // packed rounded adds
                            p23[j][i] = p23[j][i] + m23;
                        }
                }
            }
        }

        // hadd tree (l0+l1)+(l2+l3), then bias, write I chunk to LDS.
#pragma unroll
        for (int j = 0; j < 4; ++j)
#pragma unroll
            for (int i = 0; i < 4; ++i) {
                const float s01 = p01[j][i].x + p01[j][i].y;
                const float s23 = p23[j][i].x + p23[j][i].y;
                Ism[ty + 16 * j][tx + 16 * i] = (s01 + s23) + bsh[tx + 16 * i];
            }
        __syncthreads();

        // f32 LIF scan over this chunk; one thread per h.
        if (tid < BN) {
            const size_t srow0 = ((size_t)(bb * T_ + t0)) * HID_ + h0 + tid;
#pragma unroll 4
            for (int t = 0; t < BM; ++t) {
                const float It = Ism[t][tid];
                const float am = ALPHA_F * mem;   // rounded mul
                mem = am + It;                    // rounded add
                const bool fire = (mem >= 1.0f);
                spikes[srow0 + (size_t)t * HID_] = fire ? 1.0f : 0.0f;
                if (fire) mem = 0.0f;
            }
        }
        // next chunk's first slice barrier orders these Ism reads before the
        // next epilogue's Ism writes (staging only touches As/Bs).
    }

    if (tid < BN) memf[(size_t)bb * HID_ + h0 + tid] = mem;
}

extern "C" void kernel_launch(void* const* d_in, const int* in_sizes, int n_in,
                              void* d_out, int out_size, void* d_ws, size_t ws_size,
                              hipStream_t stream) {
    const float* x    = (const float*)d_in[0];   // [B,T,K] f32
    const float* W    = (const float*)d_in[1];   // [H,K] f32
    const float* bias = (const float*)d_in[2];   // [H] f32
    float* out    = (float*)d_out;
    float* spikes = out;                          // [B,T,H]
    float* memf   = out + (size_t)B_ * T_ * HID_; // [B,H]

    dim3 grid(B_, HID_ / BN);   // 64 x 16 = 1024 blocks
    snn_np_pk<<<grid, dim3(256), 0, stream>>>(x, W, bias, spikes, memf);
}

// Round 11
// 1505.248 us; speedup vs baseline: 4.8140x; 1.0455x over previous
//
#include <hip/hip_runtime.h>

// Problem constants
#define B_    64
#define T_    512
#define KDIM  1024
#define HID_  1024

// Fused tile sizes (R7/R10 skeleton: the proven no-spill configuration)
#define BM 64   // t-chunk per block iteration (8 chunks)
#define BN 64   // h-tile per block
#define BK 32   // two numpy 16-k blocks per staging slice
#define LDA 36  // padded LDS row: 32 + 4 floats (float4-aligned, breaks pow2)
#define NSLICE ((T_ / BM) * (KDIM / BK))   // 8 * 32 = 256

// f32 correctly rounded from python float math.exp(-1.0/20.0)
#define ALPHA_F 0.95122942450071400909f

typedef float v4f __attribute__((ext_vector_type(4)));
typedef float v2f __attribute__((ext_vector_type(2)));

// Bit-faithful replication of the harness numpy f32 reference (einsum
// optimize=False, SSE baseline): per output element 4 f32 accumulator lanes
// (lane l sums k = l mod 4), per 16-k block chained adds == per-lane
// descending-q accumulation (q=3,2,1,0), 16-k blocks ascending, mul and add
// separately rounded (no FMA), horizontal sum (l0+l1)+(l2+l3), one f32 bias
// add; f32 scan mem = alpha*mem + I (2 rounded ops), spike = mem>=1, reset.
// Chain byte-identical to R6..R10 (all PASSED).
//
// R11 vs R10 (1.57 ms, VALUBusy 65%): register-prefetch staging. R10 exposed
// the full global-load latency inside each barrier-locked staging phase
// (barrier -> load -> vmcnt(0) -> ds_write -> barrier). Now the next slice's
// 4 dwordx4 loads are issued during the current slice's compute phase and
// only the ds_write sits between barriers. VALU busy (~1.0 ms) is the
// structural floor: separate-rounded mul+add, no FMA allowed; v_pk_*_f32 is
// half-rate on gfx950 (157.3 TF datapath), so packing can't cut busy further.
__global__ __launch_bounds__(256, 2) void snn_np_pf(
    const float* __restrict__ x,     // [B,T,K] f32
    const float* __restrict__ W,     // [H,K] f32
    const float* __restrict__ bias,  // [H] f32
    float* __restrict__ spikes,      // [B,T,H] f32 out
    float* __restrict__ memf)        // [B,H] f32 out
{
#pragma clang fp contract(off)       // numpy SSE path has no FMA: mul+add only
    __shared__ float As[BM][LDA];      // 9.0 KB
    __shared__ float Bs[BN][LDA];      // 9.0 KB
    __shared__ float Ism[BM][BN + 1];  // 16.3 KB
    __shared__ float bsh[BN];

    const int tid = threadIdx.x;
    const int bb  = blockIdx.x;             // batch index
    const int h0  = blockIdx.y * BN;        // h tile origin

    const int tx = tid & 15;                // h micro-index (4 cols, stride 16)
    const int ty = tid >> 4;                // t micro-index (4 rows, stride 16)

    // staging: 64x32 tile = 512 float4 per matrix; each thread stages rows
    // sr0 and sr1 at col sc for both As and Bs (4 float4 total)
    const int sr0 = tid >> 3;               // 0..31
    const int sr1 = 32 + sr0;               // 32..63
    const int sc  = (tid & 7) << 2;         // 0,4,..,28

    const float* xb = x + (size_t)bb * T_ * KDIM;
    const float* Wb = W + (size_t)h0 * KDIM;

    if (tid < BN) bsh[tid] = bias[h0 + tid];

    float mem = 0.0f;                       // threads 0..63 carry h = h0+tid

    // prefetch slice 0 (chunk 0, k0 = 0) into registers
    float4 pa0 = *(const float4*)&xb[(size_t)sr0 * KDIM + sc];
    float4 pa1 = *(const float4*)&xb[(size_t)sr1 * KDIM + sc];
    float4 pw0 = *(const float4*)&Wb[(size_t)sr0 * KDIM + sc];
    float4 pw1 = *(const float4*)&Wb[(size_t)sr1 * KDIM + sc];

    for (int c = 0; c < T_ / BM; ++c) {
        const int t0 = c * BM;
        // numpy 4-lane accumulators, lane-paired: p01 = lanes {0,1}, p23 = {2,3}
        v2f p01[4][4], p23[4][4];
#pragma unroll
        for (int j = 0; j < 4; ++j)
#pragma unroll
            for (int i = 0; i < 4; ++i) {
                p01[j][i] = (v2f)(0.0f);
                p23[j][i] = (v2f)(0.0f);
            }

        for (int s = 0; s < KDIM / BK; ++s) {
            __syncthreads();   // prev slice's As/Bs readers done (+ bsh/Ism users)
            // commit prefetched slice to LDS
            *(float4*)&As[sr0][sc] = pa0;
            *(float4*)&As[sr1][sc] = pa1;
            *(float4*)&Bs[sr0][sc] = pw0;
            *(float4*)&Bs[sr1][sc] = pw1;
            // issue next slice's loads now; latency hides under compute below
            const int g1 = c * (KDIM / BK) + s + 1;
            if (g1 < NSLICE) {
                const int nt0 = (g1 >> 5) * BM;        // next chunk origin
                const int nk  = (g1 & 31) << 5;        // next k0
                pa0 = *(const float4*)&xb[(size_t)(nt0 + sr0) * KDIM + nk + sc];
                pa1 = *(const float4*)&xb[(size_t)(nt0 + sr1) * KDIM + nk + sc];
                pw0 = *(const float4*)&Wb[(size_t)sr0 * KDIM + nk + sc];
                pw1 = *(const float4*)&Wb[(size_t)sr1 * KDIM + nk + sc];
            }
            __syncthreads();   // LDS slice ready
            // two numpy 16-k blocks, ascending; q = 3,2,1,0 within each —
            // per-lane acc += a[16kb+4q+l]*b[16kb+4q+l], mul then add:
            // bitwise equal to numpy's chained a0b0+(a1b1+(a2b2+(a3b3+acc)))
#pragma unroll
            for (int kb = 0; kb < 2; ++kb) {
#pragma unroll
                for (int q = 3; q >= 0; --q) {
                    const int qc = (kb << 4) + (q << 2);
                    v2f a01[4], a23[4], b01[4], b23[4];
#pragma unroll
                    for (int j = 0; j < 4; ++j) {
                        const v4f a = *(const v4f*)&As[ty + 16 * j][qc];
                        a01[j] = a.xy; a23[j] = a.zw;
                    }
#pragma unroll
                    for (int i = 0; i < 4; ++i) {
                        const v4f b = *(const v4f*)&Bs[tx + 16 * i][qc];
                        b01[i] = b.xy; b23[i] = b.zw;
                    }
#pragma unroll
                    for (int j = 0; j < 4; ++j)
#pragma unroll
                        for (int i = 0; i < 4; ++i) {
                            const v2f m01 = a01[j] * b01[i];   // packed rounded muls
                            const v2f m23 = a23[j] * b23[i];
                            p01[j][i] = p01[j][i] + m01;       // packed rounded adds
                            p23[j][i] = p23[j][i] + m23;
                        }
                }
            }
        }

        // hadd tree (l0+l1)+(l2+l3), then bias, write I chunk to LDS.
#pragma unroll
        for (int j = 0; j < 4; ++j)
#pragma unroll
            for (int i = 0; i < 4; ++i) {
                const float s01 = p01[j][i].x + p01[j][i].y;
                const float s23 = p23[j][i].x + p23[j][i].y;
                Ism[ty + 16 * j][tx + 16 * i] = (s01 + s23) + bsh[tx + 16 * i];
            }
        __syncthreads();

        // f32 LIF scan over this chunk; one thread per h.
        if (tid < BN) {
            const size_t srow0 = ((size_t)(bb * T_ + t0)) * HID_ + h0 + tid;
#pragma unroll 4
            for (int t = 0; t < BM; ++t) {
                const float It = Ism[t][tid];
                const float am = ALPHA_F * mem;   // rounded mul
                mem = am + It;                    // rounded add
                const bool fire = (mem >= 1.0f);
                spikes[srow0 + (size_t)t * HID_] = fire ? 1.0f : 0.0f;
                if (fire) mem = 0.0f;
            }
        }
        // next chunk's first slice barrier orders these Ism reads before the
        // next epilogue's Ism writes (staging only touches As/Bs).
    }

    if (tid < BN) memf[(size_t)bb * HID_ + h0 + tid] = mem;
}

extern "C" void kernel_launch(void* const* d_in, const int* in_sizes, int n_in,
                              void* d_out, int out_size, void* d_ws, size_t ws_size,
                              hipStream_t stream) {
    const float* x    = (const float*)d_in[0];   // [B,T,K] f32
    const float* W    = (const float*)d_in[1];   // [H,K] f32
    const float* bias = (const float*)d_in[2];   // [H] f32
    float* out    = (float*)d_out;
    float* spikes = out;                          // [B,T,H]
    float* memf   = out + (size_t)B_ * T_ * HID_; // [B,H]

    dim3 grid(B_, HID_ / BN);   // 64 x 16 = 1024 blocks
    snn_np_pf<<<grid, dim3(256), 0, stream>>>(x, W, bias, spikes, memf);
}

// Round 12
// 1500.155 us; speedup vs baseline: 4.8303x; 1.0034x over previous
//
#include <hip/hip_runtime.h>

// Problem constants
#define B_    64
#define T_    512
#define KDIM  1024
#define HID_  1024

// Tile sizes (R7/R10/R11 skeleton: proven no-spill)
#define BM 64    // t-chunk per block iteration (8 chunks)
#define BN 64    // h-tile per block
#define BK 32    // two numpy 16-k blocks per slice
#define LDA 36   // padded LDS row: 32 + 4 floats
#define NSL 256  // total slices = (T_/BM)*(KDIM/BK)
#define SPC 32   // slices per chunk = KDIM/BK
#define BOFF 2304 // Bs offset within a buffer (64*36)

// f32 correctly rounded from python float math.exp(-1.0/20.0)
#define ALPHA_F 0.95122942450071400909f

typedef float v4f __attribute__((ext_vector_type(4)));
typedef float v2f __attribute__((ext_vector_type(2)));

// Bit-faithful replication of the harness numpy f32 reference (einsum
// optimize=False, SSE baseline): per output element 4 f32 accumulator lanes
// (lane l sums k = l mod 4), per-16k-block chained adds == descending-q
// accumulation, blocks ascending, mul/add separately rounded (no FMA),
// hadd tree (l0+l1)+(l2+l3), one f32 bias add; f32 scan. Chain byte-identical
// to R6..R11 (all PASSED).
//
// R12 vs R11 (1.505 ms, VALUBusy 69%, ~420 us stall): LDS double-buffer with
// ONE barrier per slice. Commit of slice g+1 (regs->buf[nxt]) and the global
// loads of slice g+2 are issued during compute on buf[g&1]; ds_write no
// longer sits between two barriers. Barriers/block 529 -> ~274. Ism aliases
// buf1 (live ranges disjoint: slice parity puts chunk-crossing commits in
// buf0; iter-0's buf1 commit is after the scan barrier). LDS 37.1 KB -> still
// 4 blocks/CU. VALU busy (~1.09 ms vs 874 us datapath floor) is structural:
// no FMA allowed, fp32 packed ops are issue-rate-equal to scalar on CDNA4.
__global__ __launch_bounds__(256, 2) void snn_np_db(
    const float* __restrict__ x,     // [B,T,K] f32
    const float* __restrict__ W,     // [H,K] f32
    const float* __restrict__ bias,  // [H] f32
    float* __restrict__ spikes,      // [B,T,H] f32 out
    float* __restrict__ memf)        // [B,H] f32 out
{
#pragma clang fp contract(off)       // numpy SSE path has no FMA: mul+add only
    __shared__ float smem[9280];     // 37120 B total
    float* const AB0 = smem;            // As0 @0, Bs0 @2304
    float* const AB1 = smem + 4608;     // As1 @4608, Bs1 @6912
    float* const Ism = smem + 4608;     // [64][65] — aliases buf1 (disjoint phases)
    float* const bsh = smem + 9216;     // [64]

    const int tid = threadIdx.x;
    const int bb  = blockIdx.x;         // batch index
    const int h0  = blockIdx.y * BN;    // h tile origin

    const int tx = tid & 15;            // h micro-index (4 cols, stride 16)
    const int ty = tid >> 4;            // t micro-index (4 rows, stride 16)

    const int sr0 = tid >> 3;           // staging rows 0..31
    const int sr1 = 32 + sr0;           // staging rows 32..63
    const int sc  = (tid & 7) << 2;     // staging col 0,4,..,28

    const float* xb = x + (size_t)bb * T_ * KDIM;
    const float* Wb = W + (size_t)h0 * KDIM;

    if (tid < BN) bsh[tid] = bias[h0 + tid];

    float mem = 0.0f;                   // threads 0..63 carry h = h0+tid

    // ---- prologue: slice 0 -> buf0; slice 1 -> regs ----
    float4 pa0, pa1, pw0, pw1;
    pa0 = *(const float4*)&xb[(size_t)sr0 * KDIM + sc];
    pa1 = *(const float4*)&xb[(size_t)sr1 * KDIM + sc];
    pw0 = *(const float4*)&Wb[(size_t)sr0 * KDIM + sc];
    pw1 = *(const float4*)&Wb[(size_t)sr1 * KDIM + sc];
    *(float4*)&AB0[sr0 * LDA + sc]        = pa0;
    *(float4*)&AB0[sr1 * LDA + sc]        = pa1;
    *(float4*)&AB0[BOFF + sr0 * LDA + sc] = pw0;
    *(float4*)&AB0[BOFF + sr1 * LDA + sc] = pw1;
    pa0 = *(const float4*)&xb[(size_t)sr0 * KDIM + 32 + sc];
    pa1 = *(const float4*)&xb[(size_t)sr1 * KDIM + 32 + sc];
    pw0 = *(const float4*)&Wb[(size_t)sr0 * KDIM + 32 + sc];
    pw1 = *(const float4*)&Wb[(size_t)sr1 * KDIM + 32 + sc];
    __syncthreads();                    // buf0 + bsh visible

    for (int c = 0; c < T_ / BM; ++c) {
        // numpy 4-lane accumulators, lane-paired: p01 = lanes {0,1}, p23 = {2,3}
        v2f p01[4][4], p23[4][4];
#pragma unroll
        for (int j = 0; j < 4; ++j)
#pragma unroll
            for (int i = 0; i < 4; ++i) {
                p01[j][i] = (v2f)(0.0f);
                p23[j][i] = (v2f)(0.0f);
            }

        for (int s = 0; s < SPC; ++s) {
            const int g = c * SPC + s;
            float* const cb = (g & 1) ? AB1 : AB0;   // compute buffer (slice g)
            float* const nb = (g & 1) ? AB0 : AB1;   // commit target (slice g+1)

            // 1) commit regs (slice g+1) into nb — overlapped with compute;
            //    nb's old readers finished before the previous barrier.
            if (g + 1 < NSL) {
                *(float4*)&nb[sr0 * LDA + sc]        = pa0;
                *(float4*)&nb[sr1 * LDA + sc]        = pa1;
                *(float4*)&nb[BOFF + sr0 * LDA + sc] = pw0;
                *(float4*)&nb[BOFF + sr1 * LDA + sc] = pw1;
            }
            // 2) issue slice g+2 loads; a whole compute phase to land.
            if (g + 2 < NSL) {
                const int gs  = g + 2;
                const int nt0 = (gs >> 5) * BM;
                const int nk  = (gs & 31) << 5;
                pa0 = *(const float4*)&xb[(size_t)(nt0 + sr0) * KDIM + nk + sc];
                pa1 = *(const float4*)&xb[(size_t)(nt0 + sr1) * KDIM + nk + sc];
                pw0 = *(const float4*)&Wb[(size_t)sr0 * KDIM + nk + sc];
                pw1 = *(const float4*)&Wb[(size_t)sr1 * KDIM + nk + sc];
            }
            // 3) compute slice g: two numpy 16-k blocks, ascending; q=3..0 —
            // per-lane acc += a[16kb+4q+l]*b[16kb+4q+l], mul then add:
            // bitwise equal to numpy's chained a0b0+(a1b1+(a2b2+(a3b3+acc)))
#pragma unroll
            for (int kb = 0; kb < 2; ++kb) {
#pragma unroll
                for (int q = 3; q >= 0; --q) {
                    const int qc = (kb << 4) + (q << 2);
                    v2f a01[4], a23[4], b01[4], b23[4];
#pragma unroll
                    for (int j = 0; j < 4; ++j) {
                        const v4f a = *(const v4f*)&cb[(ty + 16 * j) * LDA + qc];
                        a01[j] = a.xy; a23[j] = a.zw;
                    }
#pragma unroll
                    for (int i = 0; i < 4; ++i) {
                        const v4f b = *(const v4f*)&cb[BOFF + (tx + 16 * i) * LDA + qc];
                        b01[i] = b.xy; b23[i] = b.zw;
                    }
#pragma unroll
                    for (int j = 0; j < 4; ++j)
#pragma unroll
                        for (int i = 0; i < 4; ++i) {
                            const v2f m01 = a01[j] * b01[i];   // packed rounded muls
                            const v2f m23 = a23[j] * b23[i];
                            p01[j][i] = p01[j][i] + m01;       // packed rounded adds
                            p23[j][i] = p23[j][i] + m23;
                        }
                }
            }
            __syncthreads();   // slice g reads done; slice g+1 commit visible
        }

        // epilogue: hadd (l0+l1)+(l2+l3), bias, write I chunk to Ism (buf1).
        // All slice-(c*32+31) reads of buf1 completed at the loop's last barrier.
#pragma unroll
        for (int j = 0; j < 4; ++j)
#pragma unroll
            for (int i = 0; i < 4; ++i) {
                const float s01 = p01[j][i].x + p01[j][i].y;
                const float s23 = p23[j][i].x + p23[j][i].y;
                Ism[(ty + 16 * j) * (BN + 1) + (tx + 16 * i)] =
                    (s01 + s23) + bsh[tx + 16 * i];
            }
        __syncthreads();

        // f32 LIF scan over this chunk; one thread per h.
        if (tid < BN) {
            const size_t srow0 = ((size_t)(bb * T_ + c * BM)) * HID_ + h0 + tid;
#pragma unroll 4
            for (int t = 0; t < BM; ++t) {
                const float It = Ism[t * (BN + 1) + tid];
                const float am = ALPHA_F * mem;   // rounded mul
                mem = am + It;                    // rounded add
                const bool fire = (mem >= 1.0f);
                spikes[srow0 + (size_t)t * HID_] = fire ? 1.0f : 0.0f;
                if (fire) mem = 0.0f;
            }
        }
        __syncthreads();   // scan's Ism reads done before next chunk's iter-0
                           // commit into buf1 (= Ism region)
    }

    if (tid < BN) memf[(size_t)bb * HID_ + h0 + tid] = mem;
}

extern "C" void kernel_launch(void* const* d_in, const int* in_sizes, int n_in,
                              void* d_out, int out_size, void* d_ws, size_t ws_size,
                              hipStream_t stream) {
    const float* x    = (const float*)d_in[0];   // [B,T,K] f32
    const float* W    = (const float*)d_in[1];   // [H,K] f32
    const float* bias = (const float*)d_in[2];   // [H] f32
    float* out    = (float*)d_out;
    float* spikes = out;                          // [B,T,H]
    float* memf   = out + (size_t)B_ * T_ * HID_; // [B,H]

    dim3 grid(B_, HID_ / BN);   // 64 x 16 = 1024 blocks
    snn_np_db<<<grid, dim3(256), 0, stream>>>(x, W, bias, spikes, memf);
}